// Round 13
// baseline (626.532 us; speedup 1.0000x reference)
//
#include <hip/hip_runtime.h>

#define T_LEN  4096
#define KS     16
#define NCHUNK 256      // T_LEN / 16
#define LEAD   6        // consumer lags producers by 6 chunks
#define SLOTS  8        // LDS ring slots
#define BU_PAD 20       // bu row stride in dwords
#define TCOLS  65       // tile row stride: (lane*65+col) mod 32 -> 2-way max (free)

#define ALPHA_F 0.9048374180359595f
#define BETA_F  0.09516258196404048f
#define THETA_F 0.5f

// ---- pure-VALU cross-lane helpers (builtins: compiler handles DPP hazards;
// R1/R11 proved these correct on this part) --------------------------------
template<int CTRL>
__device__ __forceinline__ float dpp_max(float v) {
  int r = __builtin_amdgcn_update_dpp(0, __float_as_int(v), CTRL, 0xF, 0xF, true);
  return fmaxf(v, __int_as_float(r));
}
__device__ __forceinline__ float swap32_max(float v) {
#if __has_builtin(__builtin_amdgcn_permlane32_swap)
  auto r = __builtin_amdgcn_permlane32_swap(__float_as_int(v), __float_as_int(v), false, false);
  return fmaxf(__int_as_float((int)r[0]), __int_as_float((int)r[1]));
#else
  return fmaxf(v, __shfl_xor(v, 32, 64));
#endif
}
__device__ __forceinline__ float swap16_max(float v) {
#if __has_builtin(__builtin_amdgcn_permlane16_swap)
  auto r = __builtin_amdgcn_permlane16_swap(__float_as_int(v), __float_as_int(v), false, false);
  return fmaxf(__int_as_float((int)r[0]), __int_as_float((int)r[1]));
#else
  return fmaxf(v, __shfl_xor(v, 16, 64));
#endif
}
// global max in all lanes (butterfly, depth 6)
__device__ __forceinline__ float wave64_max_bfly(float v) {
  float m = v;
  m = dpp_max<0xB1>(m);    // xor1 (quad_perm [1,0,3,2])
  m = dpp_max<0x4E>(m);    // xor2 (quad_perm [2,3,0,1])
  m = dpp_max<0x141>(m);   // xor7 (row_half_mirror)
  m = dpp_max<0x140>(m);   // xor15 (row_mirror)
  m = swap32_max(m);
  m = swap16_max(m);
  return m;
}
// EXCLUSIVE prefix max P_i = max_{j<i} v_j (zero-fill identity; safe because
// the theta=0.5 gate makes any 0-inflation irrelevant: winners have v>=0.5>0)
__device__ __forceinline__ float scan_excl_max(float v) {
  float r = v;
  r = dpp_max<0x111>(r);   // row_shr:1
  r = dpp_max<0x112>(r);   // row_shr:2
  r = dpp_max<0x114>(r);   // row_shr:4
  r = dpp_max<0x118>(r);   // row_shr:8
  r = dpp_max<0x142>(r);   // row_bcast:15 (rows 1,3 pick up; rows 0,2 get 0 - safe)
  r = dpp_max<0x143>(r);   // row_bcast:31 (rows 2,3 pick up)
  int s = __builtin_amdgcn_update_dpp(0, __float_as_int(r), 0x138, 0xF, 0xF, true); // wave_shr:1
  return __int_as_float(s);
}

__global__ __launch_bounds__(256, 1)
void convlif_wta_kernel(const float* __restrict__ x, const float* __restrict__ W,
                        float* __restrict__ out) {
  const int b    = blockIdx.x;
  const int wave = threadIdx.x >> 6;   // 0,1,2 = producers(+flush); 3 = consumer
  const int lane = threadIdx.x & 63;   // channel k

  __shared__ float bu_lds[SLOTS][64][BU_PAD];   // 40 KB  (conv ring)
  __shared__ float tile[2][64][TCOLS];          // 32.5 KB (spike tile, dbuf)

  float* outB = out + (size_t)b * 64 * T_LEN;

  if (wave < 3) {
    // ====== producers: causal conv (round-robin mod 3) + tile flush =======
    // (verbatim from the passing R12 kernel)
    float w[KS];
    {
      const float4* w4 = reinterpret_cast<const float4*>(W + lane * KS);
      #pragma unroll
      for (int q = 0; q < 4; ++q) {
        float4 a = w4[q];
        w[4*q+0] = a.x; w[4*q+1] = a.y; w[4*q+2] = a.z; w[4*q+3] = a.w;
      }
    }
    const float4* xv4 = reinterpret_cast<const float4*>(x + (size_t)b * T_LEN);

    int myc = wave;   // my next chunk (wave, wave+3, wave+6, ...)

    for (int s = 0; s < NCHUNK + LEAD + 1; ++s) {
      if (s == myc && s < NCHUNK) {
        const int c = s;
        myc += 3;

        // xf[m] = x[16c-16+m], m = 0..31 (x[<0] treated as 0)
        float xf[32];
        if (c == 0) {
          #pragma unroll
          for (int m = 0; m < 16; ++m) xf[m] = 0.0f;
        } else {
          const int b4 = 4 * c - 4;
          #pragma unroll
          for (int q = 0; q < 4; ++q) {
            float4 a = xv4[b4 + q];
            xf[4*q+0] = a.x; xf[4*q+1] = a.y; xf[4*q+2] = a.z; xf[4*q+3] = a.w;
          }
        }
        #pragma unroll
        for (int q = 0; q < 4; ++q) {
          float4 a = xv4[4*c + q];
          xf[16+4*q+0] = a.x; xf[16+4*q+1] = a.y;
          xf[16+4*q+2] = a.z; xf[16+4*q+3] = a.w;
        }

        // u[t=16c+i] = sum_j w[j]*x[t-15+j]; summation order identical to R12
        float u[16];
        #pragma unroll
        for (int i = 0; i < 16; ++i) {
          float acc = w[0] * xf[1 + i];
          #pragma unroll
          for (int j = 1; j < KS; ++j) acc = fmaf(w[j], xf[1 + i + j], acc);
          u[i] = BETA_F * acc;
        }

        float4* dst = reinterpret_cast<float4*>(&bu_lds[c & (SLOTS-1)][lane][0]);
        dst[0] = make_float4(u[0],  u[1],  u[2],  u[3]);
        dst[1] = make_float4(u[4],  u[5],  u[6],  u[7]);
        dst[2] = make_float4(u[8],  u[9],  u[10], u[11]);
        dst[3] = make_float4(u[12], u[13], u[14], u[15]);
      }

      // flush completed 64-step tile T at s = 4T+10 (consumer finished it at
      // s-1; barrier below orders LDS writes -> these reads). Consumer reuses
      // the buffer starting s = 4T+14 -> no overlap. 192 threads, 1024 quads.
      if (s >= 10 && (s & 3) == 2) {
        const int T = (s - 10) >> 2;
        if (T < T_LEN / 64) {
          const int pl = wave * 64 + lane;     // 0..191
          const float* tb = &tile[T & 1][0][0];
          #pragma unroll
          for (int k = 0; k < 6; ++k) {
            const int idx = pl + 192 * k;      // 0..1151
            if (idx < 1024) {
              const int r  = idx >> 4;         // 0..63
              const int cq = (idx & 15) * 4;   // 0,4,...,60
              const float* src = tb + r * TCOLS + cq;
              float4 vq = make_float4(src[0], src[1], src[2], src[3]);
              *reinterpret_cast<float4*>(&outB[(size_t)r * T_LEN + T * 64 + cq]) = vq;
            }
          }
        }
      }
      __syncthreads();
    }
  } else {
    // ==== consumer: LIF + WTA, pure-VALU step (no ballot/SALU/branch) =====
    float v = 0.0f;
    float4 b0, b1, b2, b3;

    for (int s = 0; s < NCHUNK + LEAD + 1; ++s) {
      if (s == LEAD - 1) {
        const float4* src = reinterpret_cast<const float4*>(&bu_lds[0][lane][0]);
        b0 = src[0]; b1 = src[1]; b2 = src[2]; b3 = src[3];
      } else if (s >= LEAD && s < NCHUNK + LEAD) {
        const int c = s - LEAD;
        float bu[16] = { b0.x, b0.y, b0.z, b0.w,  b1.x, b1.y, b1.z, b1.w,
                         b2.x, b2.y, b2.z, b2.w,  b3.x, b3.y, b3.z, b3.w };

        float* trow = &tile[(c >> 2) & 1][lane][(c & 3) * 16];

        #pragma unroll
        for (int i = 0; i < 16; ++i) {
          v = fmaf(ALPHA_F, v, bu[i]);          // same arithmetic as R12

          // winner determination, all VALU (vcc forwarding only):
          //   m = global max; P = exclusive prefix max
          //   g = (m>=theta) ? m : INF      (theta gate)
          //   win = (v == g) && (v > P)     (first lane attaining the max)
          float m = wave64_max_bfly(v);
          float P = scan_excl_max(v);

          float g   = (m >= THETA_F) ? m : __builtin_inff();
          float sel = (v > P) ? g : __builtin_inff();
          float s01 = (v == sel) ? 1.0f : 0.0f;

          trow[i] = s01;                        // off-chain ds_write
          v = fmaf(-THETA_F, s01, v);           // exact: v-0.5 or v (s01 in {0,1})
        }

        // prefetch next chunk's bu (produced >= 1 barrier ago; slot safe)
        if (c + 1 < NCHUNK) {
          const float4* src =
              reinterpret_cast<const float4*>(&bu_lds[(c + 1) & (SLOTS-1)][lane][0]);
          b0 = src[0]; b1 = src[1]; b2 = src[2]; b3 = src[3];
        }
      }
      __syncthreads();
    }
  }
}

extern "C" void kernel_launch(void* const* d_in, const int* in_sizes, int n_in,
                              void* d_out, int out_size, void* d_ws, size_t ws_size,
                              hipStream_t stream) {
  const float* x   = (const float*)d_in[0];
  const float* W   = (const float*)d_in[1];
  float*       out = (float*)d_out;
  convlif_wta_kernel<<<dim3(256), dim3(256), 0, stream>>>(x, W, out);
}

// Round 14
// 255.808 us; speedup vs baseline: 2.4492x; 2.4492x over previous
//
#include <hip/hip_runtime.h>

#define T_LEN  4096
#define KS     16
#define NCHUNK 256      // T_LEN / 16
#define LEAD   6        // consumer lags producers by 6 chunks
#define SLOTS  8        // LDS ring slots
#define BU_PAD 20       // bu row stride in dwords
#define TCOLS  65       // tile row stride: (lane*65+col) mod 32 -> 2-way max (free)

#define ALPHA_F 0.9048374180359595f
#define BETA_F  0.09516258196404048f
#define THETA_F 0.5f

// Full-wave (64-lane) max, result in ALL lanes. 4 fused DPP max levels, then
// permlane32_swap / permlane16_swap + max. Manual s_nop 1 before every
// DPP/permlane consumer (VALU->DPP needs 2 wait states; compiler can't see
// inside the asm block). Verbatim from the passing R3/R4/R5/R7/R8/R10/R12.
__device__ __forceinline__ float wave64_max_all(float v) {
  float m, t;
  asm("s_nop 1\n\t"
      "v_max_f32 %0, %2, %2 quad_perm:[1,0,3,2] row_mask:0xf bank_mask:0xf\n\t"
      "s_nop 1\n\t"
      "v_max_f32 %0, %0, %0 quad_perm:[2,3,0,1] row_mask:0xf bank_mask:0xf\n\t"
      "s_nop 1\n\t"
      "v_max_f32 %0, %0, %0 row_half_mirror row_mask:0xf bank_mask:0xf\n\t"
      "s_nop 1\n\t"
      "v_max_f32 %0, %0, %0 row_mirror row_mask:0xf bank_mask:0xf\n\t"
      "v_mov_b32 %1, %0\n\t"
      "s_nop 1\n\t"
      "v_permlane32_swap_b32 %1, %0\n\t"
      "s_nop 1\n\t"
      "v_max_f32 %0, %0, %1\n\t"
      "v_mov_b32 %1, %0\n\t"
      "s_nop 1\n\t"
      "v_permlane16_swap_b32 %1, %0\n\t"
      "s_nop 1\n\t"
      "v_max_f32 %0, %0, %1"
      : "=&v"(m), "=&v"(t)
      : "v"(v));
  return m;
}

__global__ __launch_bounds__(256, 1)
void convlif_wta_kernel(const float* __restrict__ x, const float* __restrict__ W,
                        float* __restrict__ out) {
  const int b    = blockIdx.x;
  const int wave = threadIdx.x >> 6;   // 0,1,2 = producers(+flush); 3 = consumer
  const int lane = threadIdx.x & 63;   // channel k

  __shared__ float bu_lds[SLOTS][64][BU_PAD];   // 40 KB  (conv ring)
  __shared__ float tile[2][64][TCOLS];          // 32.5 KB (spike tile, dbuf)

  float* outB = out + (size_t)b * 64 * T_LEN;

  if (wave < 3) {
    // ====== producers: causal conv (round-robin mod 3) + tile flush =======
    // (verbatim from the passing R12 kernel)
    float w[KS];
    {
      const float4* w4 = reinterpret_cast<const float4*>(W + lane * KS);
      #pragma unroll
      for (int q = 0; q < 4; ++q) {
        float4 a = w4[q];
        w[4*q+0] = a.x; w[4*q+1] = a.y; w[4*q+2] = a.z; w[4*q+3] = a.w;
      }
    }
    const float4* xv4 = reinterpret_cast<const float4*>(x + (size_t)b * T_LEN);

    int myc = wave;   // my next chunk (wave, wave+3, wave+6, ...)

    for (int s = 0; s < NCHUNK + LEAD + 1; ++s) {
      if (s == myc && s < NCHUNK) {
        const int c = s;
        myc += 3;

        // xf[m] = x[16c-16+m], m = 0..31 (x[<0] treated as 0)
        float xf[32];
        if (c == 0) {
          #pragma unroll
          for (int m = 0; m < 16; ++m) xf[m] = 0.0f;
        } else {
          const int b4 = 4 * c - 4;
          #pragma unroll
          for (int q = 0; q < 4; ++q) {
            float4 a = xv4[b4 + q];
            xf[4*q+0] = a.x; xf[4*q+1] = a.y; xf[4*q+2] = a.z; xf[4*q+3] = a.w;
          }
        }
        #pragma unroll
        for (int q = 0; q < 4; ++q) {
          float4 a = xv4[4*c + q];
          xf[16+4*q+0] = a.x; xf[16+4*q+1] = a.y;
          xf[16+4*q+2] = a.z; xf[16+4*q+3] = a.w;
        }

        // u[t=16c+i] = sum_j w[j]*x[t-15+j]; summation order identical to R12
        float u[16];
        #pragma unroll
        for (int i = 0; i < 16; ++i) {
          float acc = w[0] * xf[1 + i];
          #pragma unroll
          for (int j = 1; j < KS; ++j) acc = fmaf(w[j], xf[1 + i + j], acc);
          u[i] = BETA_F * acc;
        }

        float4* dst = reinterpret_cast<float4*>(&bu_lds[c & (SLOTS-1)][lane][0]);
        dst[0] = make_float4(u[0],  u[1],  u[2],  u[3]);
        dst[1] = make_float4(u[4],  u[5],  u[6],  u[7]);
        dst[2] = make_float4(u[8],  u[9],  u[10], u[11]);
        dst[3] = make_float4(u[12], u[13], u[14], u[15]);
      }

      // flush completed 64-step tile T at s = 4T+10 (consumer finished it at
      // s-1; barrier below orders LDS writes -> these reads). Consumer reuses
      // the buffer starting s = 4T+14 -> no overlap. 192 threads, 1024 quads.
      if (s >= 10 && (s & 3) == 2) {
        const int T = (s - 10) >> 2;
        if (T < T_LEN / 64) {
          const int pl = wave * 64 + lane;     // 0..191
          const float* tb = &tile[T & 1][0][0];
          #pragma unroll
          for (int k = 0; k < 6; ++k) {
            const int idx = pl + 192 * k;      // 0..1151
            if (idx < 1024) {
              const int r  = idx >> 4;         // 0..63
              const int cq = (idx & 15) * 4;   // 0,4,...,60
              const float* src = tb + r * TCOLS + cq;
              float4 vq = make_float4(src[0], src[1], src[2], src[3]);
              *reinterpret_cast<float4*>(&outB[(size_t)r * T_LEN + T * 64 + cq]) = vq;
            }
          }
        }
      }
      __syncthreads();
    }
  } else {
    // == consumer: blind-apply LIF + WTA; cross-lane work only on fix path ==
    // Common path (popcount(candidates)<=1, ~83% of steps): the winner mask
    // restricted to this lane IS the lane's own candidacy bit, so
    //   sv = (v>=theta), v -= theta*(v>=theta)
    // needs NO cross-lane ops: fma -> v_cmp -> cndmask = 3 dependent links.
    // Multi-candidate steps are detected off-path (SALU popcount of the
    // ballot) and repaired exactly with the proven reduce+ctz logic.
    float v = 0.0f;
    float4 b0, b1, b2, b3;

    for (int s = 0; s < NCHUNK + LEAD + 1; ++s) {
      if (s == LEAD - 1) {
        const float4* src = reinterpret_cast<const float4*>(&bu_lds[0][lane][0]);
        b0 = src[0]; b1 = src[1]; b2 = src[2]; b3 = src[3];
      } else if (s >= LEAD && s < NCHUNK + LEAD) {
        const int c = s - LEAD;
        float bu[16] = { b0.x, b0.y, b0.z, b0.w,  b1.x, b1.y, b1.z, b1.w,
                         b2.x, b2.y, b2.z, b2.w,  b3.x, b3.y, b3.z, b3.w };

        float sv[16];

        #pragma unroll
        for (int i = 0; i < 16; ++i) {
          float vr = fmaf(ALPHA_F, v, bu[i]);   // raw state (same arithmetic)
          float vm = vr - THETA_F;              // exact; (vm>=0) <=> (vr>=theta)

          unsigned long long sp = __ballot(vr >= THETA_F);  // one v_cmp -> sgpr
          bool c1 = (vr >= THETA_F);            // same compare, reused

          // blind apply (exact when <=1 candidate)
          sv[i] = c1 ? 1.0f : 0.0f;
          v     = c1 ? vm : vr;

          // multi-candidate repair (rare): exact R10/R12 winner logic
          if (__builtin_expect((sp & (sp - 1ull)) != 0ull, 0)) {
            float m = wave64_max_all(vr);
            unsigned long long eq = __ballot(vr == m);
            int wl = __builtin_ctzll(eq);       // first max lane = argmax
            bool win = (lane == wl);
            sv[i] = win ? 1.0f : 0.0f;
            v     = win ? vm : vr;
          }
        }

        // flush chunk results: 4 x ds_write_b128, conflict-free (TCOLS=65)
        float* trow = &tile[(c >> 2) & 1][lane][(c & 3) * 16];
        *reinterpret_cast<float4*>(trow +  0) = make_float4(sv[0],  sv[1],  sv[2],  sv[3]);
        *reinterpret_cast<float4*>(trow +  4) = make_float4(sv[4],  sv[5],  sv[6],  sv[7]);
        *reinterpret_cast<float4*>(trow +  8) = make_float4(sv[8],  sv[9],  sv[10], sv[11]);
        *reinterpret_cast<float4*>(trow + 12) = make_float4(sv[12], sv[13], sv[14], sv[15]);

        // prefetch next chunk's bu (produced >= 1 barrier ago; slot safe)
        if (c + 1 < NCHUNK) {
          const float4* src =
              reinterpret_cast<const float4*>(&bu_lds[(c + 1) & (SLOTS-1)][lane][0]);
          b0 = src[0]; b1 = src[1]; b2 = src[2]; b3 = src[3];
        }
      }
      __syncthreads();
    }
  }
}

extern "C" void kernel_launch(void* const* d_in, const int* in_sizes, int n_in,
                              void* d_out, int out_size, void* d_ws, size_t ws_size,
                              hipStream_t stream) {
  const float* x   = (const float*)d_in[0];
  const float* W   = (const float*)d_in[1];
  float*       out = (float*)d_out;
  convlif_wta_kernel<<<dim3(256), dim3(256), 0, stream>>>(x, W, out);
}

// Round 15
// 141.402 us; speedup vs baseline: 4.4309x; 1.8091x over previous
//
#include <hip/hip_runtime.h>

#define T_LEN  4096
#define KS     16
#define NSEG   16          // T segments (256 output steps each)
#define SEG_CH 16          // output chunks per segment
#define WARM_CH 32         // 512 warm-up steps: alpha^512 ~ e^-51 -> bit-coalesced

#define ALPHA_F 0.9048374180359595f
#define BETA_F  0.09516258196404048f
#define THETA_F 0.5f

// Full-wave (64-lane) max, result in ALL lanes. Verbatim from the passing
// R3-R14 kernels (manual s_nop hazard handling inside asm).
__device__ __forceinline__ float wave64_max_all(float v) {
  float m, t;
  asm("s_nop 1\n\t"
      "v_max_f32 %0, %2, %2 quad_perm:[1,0,3,2] row_mask:0xf bank_mask:0xf\n\t"
      "s_nop 1\n\t"
      "v_max_f32 %0, %0, %0 quad_perm:[2,3,0,1] row_mask:0xf bank_mask:0xf\n\t"
      "s_nop 1\n\t"
      "v_max_f32 %0, %0, %0 row_half_mirror row_mask:0xf bank_mask:0xf\n\t"
      "s_nop 1\n\t"
      "v_max_f32 %0, %0, %0 row_mirror row_mask:0xf bank_mask:0xf\n\t"
      "v_mov_b32 %1, %0\n\t"
      "s_nop 1\n\t"
      "v_permlane32_swap_b32 %1, %0\n\t"
      "s_nop 1\n\t"
      "v_max_f32 %0, %0, %1\n\t"
      "v_mov_b32 %1, %0\n\t"
      "s_nop 1\n\t"
      "v_permlane16_swap_b32 %1, %0\n\t"
      "s_nop 1\n\t"
      "v_max_f32 %0, %0, %1"
      : "=&v"(m), "=&v"(t)
      : "v"(v));
  return m;
}

__global__ __launch_bounds__(64, 4)
void convlif_wta_kernel(const float* __restrict__ x, const float* __restrict__ W,
                        float* __restrict__ out) {
  const int blk  = blockIdx.x;
  const int b    = blk >> 4;          // batch
  const int seg  = blk & (NSEG - 1);  // time segment
  const int lane = threadIdx.x;       // channel k

  const int cout0  = seg * SEG_CH;                                  // first output chunk
  const int cstart = (cout0 > WARM_CH) ? (cout0 - WARM_CH) : 0;     // warm-up start
  const int cend   = cout0 + SEG_CH;

  // per-lane conv weights W[k][0..15]
  float w[KS];
  {
    const float4* w4 = reinterpret_cast<const float4*>(W + lane * KS);
    #pragma unroll
    for (int q = 0; q < 4; ++q) {
      float4 a = w4[q];
      w[4*q+0] = a.x; w[4*q+1] = a.y; w[4*q+2] = a.z; w[4*q+3] = a.w;
    }
  }

  const float4* xv4 = reinterpret_cast<const float4*>(x + (size_t)b * T_LEN);
  float* orow = out + ((size_t)(b * 64 + lane)) * T_LEN;   // this lane's channel row

  // rolling x window: cur[0..7] = quads 4c-4 .. 4c+3 = x[16c-16 .. 16c+15]
  // (for c==0 the first half is garbage; overridden with zeros at xf assembly)
  float4 cur[8];
  {
    const int c  = cstart;
    const int bq = 4 * c - 4;
    const int b0 = (bq < 0) ? 0 : bq;
    #pragma unroll
    for (int q = 0; q < 4; ++q) cur[q] = xv4[b0 + q];
    #pragma unroll
    for (int q = 0; q < 4; ++q) cur[4 + q] = xv4[4 * c + q];
  }

  float v = 0.0f;   // exact for seg 0-2 (warm-up covers from t=0); speculative else

  for (int c = cstart; c < cend; ++c) {
    // prefetch the 4 NEW quads of the next chunk (rolling: next chunk's first
    // 4 quads == current chunk's last 4)
    float4 nx0, nx1, nx2, nx3;
    {
      const int cn = (c + 1 < cend) ? (c + 1) : c;   // clamp; cn >= 1 always used
      nx0 = xv4[4 * cn + 0]; nx1 = xv4[4 * cn + 1];
      nx2 = xv4[4 * cn + 2]; nx3 = xv4[4 * cn + 3];
    }

    // assemble xf[m] = x[16c-16+m], m=0..31 (x[<0] = 0)
    float xf[32];
    if (c == 0) {
      #pragma unroll
      for (int m = 0; m < 16; ++m) xf[m] = 0.0f;
    } else {
      #pragma unroll
      for (int q = 0; q < 4; ++q) {
        xf[4*q+0] = cur[q].x; xf[4*q+1] = cur[q].y;
        xf[4*q+2] = cur[q].z; xf[4*q+3] = cur[q].w;
      }
    }
    #pragma unroll
    for (int q = 0; q < 4; ++q) {
      xf[16+4*q+0] = cur[4+q].x; xf[16+4*q+1] = cur[4+q].y;
      xf[16+4*q+2] = cur[4+q].z; xf[16+4*q+3] = cur[4+q].w;
    }

    // u[t=16c+i] = BETA * sum_j w[j]*x[t-15+j]; summation order identical to
    // all passing rounds (R5-R14)
    float u[16];
    #pragma unroll
    for (int i = 0; i < 16; ++i) {
      float acc = w[0] * xf[1 + i];
      #pragma unroll
      for (int j = 1; j < KS; ++j) acc = fmaf(w[j], xf[1 + i + j], acc);
      u[i] = BETA_F * acc;
    }

    // 16 LIF+WTA steps: R14's verbatim blind-apply + rare multi-candidate fix
    float sv[16];
    #pragma unroll
    for (int i = 0; i < 16; ++i) {
      float vr = fmaf(ALPHA_F, v, u[i]);      // raw state (same arithmetic)
      float vm = vr - THETA_F;                // exact; (vm>=0) <=> (vr>=theta)

      unsigned long long sp = __ballot(vr >= THETA_F);
      bool c1 = (vr >= THETA_F);

      // blind apply (exact when <=1 candidate)
      sv[i] = c1 ? 1.0f : 0.0f;
      v     = c1 ? vm : vr;

      // multi-candidate repair (rare): exact R10/R12/R14 winner logic
      if (__builtin_expect((sp & (sp - 1ull)) != 0ull, 0)) {
        float m = wave64_max_all(vr);
        unsigned long long eq = __ballot(vr == m);
        int wl = __builtin_ctzll(eq);         // first max lane = argmax
        bool win = (lane == wl);
        sv[i] = win ? 1.0f : 0.0f;
        v     = win ? vm : vr;
      }
    }

    // output window: each lane stores its own row, 64 B contiguous.
    // Adjacent chunks complete 128-B lines in L2 -> no write amplification.
    if (c >= cout0) {
      float4* p = reinterpret_cast<float4*>(orow + (size_t)c * 16);
      p[0] = make_float4(sv[0],  sv[1],  sv[2],  sv[3]);
      p[1] = make_float4(sv[4],  sv[5],  sv[6],  sv[7]);
      p[2] = make_float4(sv[8],  sv[9],  sv[10], sv[11]);
      p[3] = make_float4(sv[12], sv[13], sv[14], sv[15]);
    }

    // roll window: next chunk's quads 0..3 = current quads 4..7
    cur[0] = cur[4]; cur[1] = cur[5]; cur[2] = cur[6]; cur[3] = cur[7];
    cur[4] = nx0;    cur[5] = nx1;    cur[6] = nx2;    cur[7] = nx3;
  }
}

extern "C" void kernel_launch(void* const* d_in, const int* in_sizes, int n_in,
                              void* d_out, int out_size, void* d_ws, size_t ws_size,
                              hipStream_t stream) {
  const float* x   = (const float*)d_in[0];
  const float* W   = (const float*)d_in[1];
  float*       out = (float*)d_out;
  convlif_wta_kernel<<<dim3(256 * NSEG), dim3(64), 0, stream>>>(x, W, out);
}

// Round 16
// 125.886 us; speedup vs baseline: 4.9770x; 1.1233x over previous
//
#include <hip/hip_runtime.h>

#define T_LEN  4096
#define KS     16
#define NSEG   16          // T segments (256 output steps each)
#define SEG_CH 16          // output chunks per segment
#define WARM_CH 24         // 384 warm-up steps; flips cease by warm-190 (see margin calc)

#define ALPHA_F 0.9048374180359595f
#define BETA_F  0.09516258196404048f
#define THETA_F 0.5f

// Full-wave (64-lane) max, result in ALL lanes. Verbatim from the passing
// R3-R15 kernels (manual s_nop hazard handling inside asm).
__device__ __forceinline__ float wave64_max_all(float v) {
  float m, t;
  asm("s_nop 1\n\t"
      "v_max_f32 %0, %2, %2 quad_perm:[1,0,3,2] row_mask:0xf bank_mask:0xf\n\t"
      "s_nop 1\n\t"
      "v_max_f32 %0, %0, %0 quad_perm:[2,3,0,1] row_mask:0xf bank_mask:0xf\n\t"
      "s_nop 1\n\t"
      "v_max_f32 %0, %0, %0 row_half_mirror row_mask:0xf bank_mask:0xf\n\t"
      "s_nop 1\n\t"
      "v_max_f32 %0, %0, %0 row_mirror row_mask:0xf bank_mask:0xf\n\t"
      "v_mov_b32 %1, %0\n\t"
      "s_nop 1\n\t"
      "v_permlane32_swap_b32 %1, %0\n\t"
      "s_nop 1\n\t"
      "v_max_f32 %0, %0, %1\n\t"
      "v_mov_b32 %1, %0\n\t"
      "s_nop 1\n\t"
      "v_permlane16_swap_b32 %1, %0\n\t"
      "s_nop 1\n\t"
      "v_max_f32 %0, %0, %1"
      : "=&v"(m), "=&v"(t)
      : "v"(v));
  return m;
}

__global__ __launch_bounds__(64, 4)
void convlif_wta_kernel(const float* __restrict__ x, const float* __restrict__ W,
                        float* __restrict__ out) {
  const int blk  = blockIdx.x;
  const int b    = blk >> 4;          // batch
  const int seg  = blk & (NSEG - 1);  // time segment
  const int lane = threadIdx.x;       // channel k

  const int cout0  = seg * SEG_CH;                                  // first output chunk
  const int cstart = (cout0 > WARM_CH) ? (cout0 - WARM_CH) : 0;     // warm-up start
  const int cend   = cout0 + SEG_CH;

  // per-lane conv weights W[k][0..15]
  float w[KS];
  {
    const float4* w4 = reinterpret_cast<const float4*>(W + lane * KS);
    #pragma unroll
    for (int q = 0; q < 4; ++q) {
      float4 a = w4[q];
      w[4*q+0] = a.x; w[4*q+1] = a.y; w[4*q+2] = a.z; w[4*q+3] = a.w;
    }
  }

  const float4* xv4 = reinterpret_cast<const float4*>(x + (size_t)b * T_LEN);
  float* orow = out + ((size_t)(b * 64 + lane)) * T_LEN;   // this lane's channel row

  // rolling x window: cur[0..7] = quads 4c-4 .. 4c+3 = x[16c-16 .. 16c+15]
  // (for c==0 the first half is garbage; overridden with zeros at xf assembly)
  float4 cur[8];
  {
    const int c  = cstart;
    const int bq = 4 * c - 4;
    const int b0 = (bq < 0) ? 0 : bq;
    #pragma unroll
    for (int q = 0; q < 4; ++q) cur[q] = xv4[b0 + q];
    #pragma unroll
    for (int q = 0; q < 4; ++q) cur[4 + q] = xv4[4 * c + q];
  }

  float v = 0.0f;   // exact for seg 0-1 (warm-up reaches t=0); speculative else

  // ---------------- phase 1: warm-up (no sv, no stores) -------------------
  for (int c = cstart; c < cout0; ++c) {
    float4 nx0 = xv4[4*(c+1) + 0], nx1 = xv4[4*(c+1) + 1];   // c+1 <= cout0 < cend
    float4 nx2 = xv4[4*(c+1) + 2], nx3 = xv4[4*(c+1) + 3];

    float xf[32];
    if (c == 0) {
      #pragma unroll
      for (int m = 0; m < 16; ++m) xf[m] = 0.0f;
    } else {
      #pragma unroll
      for (int q = 0; q < 4; ++q) {
        xf[4*q+0] = cur[q].x; xf[4*q+1] = cur[q].y;
        xf[4*q+2] = cur[q].z; xf[4*q+3] = cur[q].w;
      }
    }
    #pragma unroll
    for (int q = 0; q < 4; ++q) {
      xf[16+4*q+0] = cur[4+q].x; xf[16+4*q+1] = cur[4+q].y;
      xf[16+4*q+2] = cur[4+q].z; xf[16+4*q+3] = cur[4+q].w;
    }

    // u exactly as all passing rounds (same summation order)
    float u[16];
    #pragma unroll
    for (int i = 0; i < 16; ++i) {
      float acc = w[0] * xf[1 + i];
      #pragma unroll
      for (int j = 1; j < KS; ++j) acc = fmaf(w[j], xf[1 + i + j], acc);
      u[i] = BETA_F * acc;
    }

    // lean LIF step: state update only (blind apply + rare exact repair)
    #pragma unroll
    for (int i = 0; i < 16; ++i) {
      float vr = fmaf(ALPHA_F, v, u[i]);
      float vm = vr - THETA_F;
      unsigned long long sp = __ballot(vr >= THETA_F);
      bool c1 = (vr >= THETA_F);
      v = c1 ? vm : vr;
      if (__builtin_expect((sp & (sp - 1ull)) != 0ull, 0)) {
        float m = wave64_max_all(vr);
        unsigned long long eq = __ballot(vr == m);
        bool win = (lane == __builtin_ctzll(eq));
        v = win ? vm : vr;
      }
    }

    cur[0] = cur[4]; cur[1] = cur[5]; cur[2] = cur[6]; cur[3] = cur[7];
    cur[4] = nx0;    cur[5] = nx1;    cur[6] = nx2;    cur[7] = nx3;
  }

  // ---------------- phase 2: output window --------------------------------
  for (int c = cout0; c < cend; ++c) {
    float4 nx0, nx1, nx2, nx3;
    {
      const int cn = (c + 1 < cend) ? (c + 1) : c;   // clamp on last chunk
      nx0 = xv4[4*cn + 0]; nx1 = xv4[4*cn + 1];
      nx2 = xv4[4*cn + 2]; nx3 = xv4[4*cn + 3];
    }

    float xf[32];
    if (c == 0) {
      #pragma unroll
      for (int m = 0; m < 16; ++m) xf[m] = 0.0f;
    } else {
      #pragma unroll
      for (int q = 0; q < 4; ++q) {
        xf[4*q+0] = cur[q].x; xf[4*q+1] = cur[q].y;
        xf[4*q+2] = cur[q].z; xf[4*q+3] = cur[q].w;
      }
    }
    #pragma unroll
    for (int q = 0; q < 4; ++q) {
      xf[16+4*q+0] = cur[4+q].x; xf[16+4*q+1] = cur[4+q].y;
      xf[16+4*q+2] = cur[4+q].z; xf[16+4*q+3] = cur[4+q].w;
    }

    float u[16];
    #pragma unroll
    for (int i = 0; i < 16; ++i) {
      float acc = w[0] * xf[1 + i];
      #pragma unroll
      for (int j = 1; j < KS; ++j) acc = fmaf(w[j], xf[1 + i + j], acc);
      u[i] = BETA_F * acc;
    }

    // full LIF+WTA step (verbatim R14/R15 semantics)
    float sv[16];
    #pragma unroll
    for (int i = 0; i < 16; ++i) {
      float vr = fmaf(ALPHA_F, v, u[i]);
      float vm = vr - THETA_F;
      unsigned long long sp = __ballot(vr >= THETA_F);
      bool c1 = (vr >= THETA_F);
      sv[i] = c1 ? 1.0f : 0.0f;
      v     = c1 ? vm : vr;
      if (__builtin_expect((sp & (sp - 1ull)) != 0ull, 0)) {
        float m = wave64_max_all(vr);
        unsigned long long eq = __ballot(vr == m);
        bool win = (lane == __builtin_ctzll(eq));
        sv[i] = win ? 1.0f : 0.0f;
        v     = win ? vm : vr;
      }
    }

    float4* p = reinterpret_cast<float4*>(orow + (size_t)c * 16);
    p[0] = make_float4(sv[0],  sv[1],  sv[2],  sv[3]);
    p[1] = make_float4(sv[4],  sv[5],  sv[6],  sv[7]);
    p[2] = make_float4(sv[8],  sv[9],  sv[10], sv[11]);
    p[3] = make_float4(sv[12], sv[13], sv[14], sv[15]);

    cur[0] = cur[4]; cur[1] = cur[5]; cur[2] = cur[6]; cur[3] = cur[7];
    cur[4] = nx0;    cur[5] = nx1;    cur[6] = nx2;    cur[7] = nx3;
  }
}

extern "C" void kernel_launch(void* const* d_in, const int* in_sizes, int n_in,
                              void* d_out, int out_size, void* d_ws, size_t ws_size,
                              hipStream_t stream) {
  const float* x   = (const float*)d_in[0];
  const float* W   = (const float*)d_in[1];
  float*       out = (float*)d_out;
  convlif_wta_kernel<<<dim3(256 * NSEG), dim3(64), 0, stream>>>(x, W, out);
}